// Round 6
// baseline (494.047 us; speedup 1.0000x reference)
//
#include <hip/hip_runtime.h>

#define NNODES 2000
#define BATCH  64
#define DIM    256
#define BLOCK  128
#define MAXGRID 1024

typedef __attribute__((ext_vector_type(8))) short  v8s;
typedef __attribute__((ext_vector_type(8))) __bf16 v8bf;
typedef __attribute__((ext_vector_type(4))) float  v4f;
typedef __attribute__((ext_vector_type(4))) int    v4i;

__device__ __forceinline__ short f2bf(float f) {
  unsigned u = __builtin_bit_cast(unsigned, f);
  u += 0x7FFFu + ((u >> 16) & 1u);            // RNE
  return (short)(u >> 16);
}
__device__ __forceinline__ float bf2f(short s) {
  unsigned u = ((unsigned)(unsigned short)s) << 16;
  return __builtin_bit_cast(float, u);
}
__device__ __forceinline__ v4f mfma16(v8s a, v8s b, v4f c) {
  return __builtin_amdgcn_mfma_f32_16x16x32_bf16(
      __builtin_bit_cast(v8bf, a), __builtin_bit_cast(v8bf, b), c, 0, 0, 0);
}
__device__ __forceinline__ float sigmoidf(float x) {
  return __builtin_amdgcn_rcpf(1.0f + __builtin_amdgcn_exp2f(-1.4426950408889634f * x));
}

// Prep: Wt_in[j][k] = bf16(W_in[k][j]) (256x256);
//       Wt_inner[j][k] = bf16(k<256 ? W_inner[k][j]+W_inner[k+256][j] : W_inner[k+256][j]) (256x512);
//       done[] = 0 (agent-scope so tree_kernel's relaxed loads see it).
__global__ void prep_kernel(const float* __restrict__ W_in, const float* __restrict__ W_inner,
                            short* __restrict__ Wt_in, short* __restrict__ Wt_inner,
                            int* __restrict__ done) {
  int idx = blockIdx.x * blockDim.x + threadIdx.x;
  int stride = gridDim.x * blockDim.x;
  for (int i = idx; i < 256 * 256; i += stride) {
    int j = i >> 8, k = i & 255;
    Wt_in[j * 256 + k] = f2bf(W_in[k * 256 + j]);
  }
  for (int i = idx; i < 256 * 512; i += stride) {
    int j = i >> 9, k = i & 511;
    float v = W_inner[(k + 256) * 256 + j];
    if (k < 256) v += W_inner[k * 256 + j];
    Wt_inner[j * 512 + k] = f2bf(v);
  }
  for (int i = idx; i < 4 * NNODES; i += stride)
    __hip_atomic_store(&done[i], 0, __ATOMIC_RELAXED, __HIP_MEMORY_SCOPE_AGENT);
}

// Dataflow tree evaluation, zero cache-flush fences (R4-verified sc0sc1/IF scheme).
// R4/R5 showed wall = (items per block) x (per-item EXPOSED LATENCY): blocks run in
// parallel, rarely poll-blocked, each ~85% stalled within an item (IF round-trips,
// L2 W loads, store drains) at only 2 blocks/CU (32KB Xs vs 64KB shared-mem model).
// R6: quarter-node work items (16 batch rows) -> Xs = 16KB -> 4 blocks/CU (8 waves,
// 4 independent chains/CU to overlap stalls) and ~half the per-item work.
// Item = 4*node + q; q covers batch rows [16q, 16q+16) -- an end-to-end independent
// chain. Deps of an item have strictly larger item index; blocks walk items
// descending strided by gridDim.x; all blocks co-resident (cooperative launch with
// occupancy-derived grid) => highest-index unfinished item is always runnable.
__launch_bounds__(BLOCK, 2)
__global__ void tree_kernel(const int* __restrict__ structure, const float* __restrict__ features,
                            const float* __restrict__ b_in, const float* __restrict__ b_inner,
                            const short* __restrict__ Wt_in, const short* __restrict__ Wt_inner,
                            short* __restrict__ state, int* done, float* __restrict__ out) {
  // 16 batch rows x 512 k (bf16), XOR-swizzled chunks: phys chunk = (k>>3) ^ (row&7).
  __shared__ short Xs[16 * 512];   // 16 KiB

  const int tid  = threadIdx.x;
  const int wave = tid >> 6;       // 0..1
  const int lane = tid & 63;
  const int ln15 = lane & 15;
  const int quad = lane >> 4;
  const int rl3  = ln15 & 7;

  const int bl  = tid >> 3;        // 0..15: batch row (within quarter) this thread pools
  const int d0  = (tid & 7) << 5;  // dim block [d0, d0+32)
  const int swb = bl & 7;

  // j = wave*128 + nt*16 + ln15 is node-invariant: hoist bias loads
  float bia_in[8], bia_nn[8];
  #pragma unroll
  for (int nt = 0; nt < 8; ++nt) {
    const int j = wave * 128 + nt * 16 + ln15;
    bia_in[nt] = b_in[j];
    bia_nn[nt] = b_inner[j];
  }

  for (int item = 4 * NNODES - 1 - (int)blockIdx.x; item >= 0; item -= (int)gridDim.x) {
    const int node = item >> 2;
    const int q    = item & 3;
    const int s = structure[2 * node];
    const int e = structure[2 * node + 1];
    const bool leaf = (s < 0);
    const int nc = e - s;               // 1..4 when inner
    const int K = leaf ? 256 : 512;
    const short* __restrict__ W = leaf ? Wt_in : Wt_inner;

    const int b = q * 16 + bl;          // this thread's batch row
    // prefetch features BEFORE the poll: hides HBM/L3 latency under the wait
    const float* __restrict__ fp = features + ((size_t)b * NNODES + node) * DIM + d0;
    float4 pre[8];
    #pragma unroll
    for (int qq = 0; qq < 8; ++qq) pre[qq] = ((const float4*)fp)[qq];

    if (!leaf && wave == 0 && lane < nc) {
      // relaxed agent-scope poll (reads IF, no cache invalidation)
      int g = 0;
      while (__hip_atomic_load(&done[4 * (s + lane) + q],
                               __ATOMIC_RELAXED, __HIP_MEMORY_SCOPE_AGENT) == 0 &&
             g < (1 << 22)) {
        __builtin_amdgcn_s_sleep(1); ++g;
      }
    }
    __syncthreads();   // children's quarter ready; also WAR on Xs from prior item

    // ---- build Xs (bf16) for the quarter's 16 batch rows ----
    if (leaf) {
      #pragma unroll
      for (int dq = 0; dq < 4; ++dq) {
        const float4 f0 = pre[2 * dq];
        const float4 f1 = pre[2 * dq + 1];
        v8s o;
        o[0] = f2bf(f0.x); o[1] = f2bf(f0.y); o[2] = f2bf(f0.z); o[3] = f2bf(f0.w);
        o[4] = f2bf(f1.x); o[5] = f2bf(f1.y); o[6] = f2bf(f1.z); o[7] = f2bf(f1.w);
        const int ch = (d0 + dq * 8) >> 3;
        *(v8s*)&Xs[(bl << 9) + ((ch ^ swb) << 3)] = o;
      }
    } else {
      // issue ALL child loads (sc0 sc1: bypass stale L1/L2, coherent at IF),
      // then one waitcnt -- IF latency paid once.
      v4i cb[4][4];
      #pragma unroll
      for (int ci = 0; ci < 4; ++ci) {
        if (ci < nc) {   // block-uniform branch
          const short* cp = state + ((size_t)(s + ci) * BATCH + b) * DIM + d0;
          #pragma unroll
          for (int dq = 0; dq < 4; ++dq)
            asm volatile("global_load_dwordx4 %0, %1, off sc0 sc1"
                         : "=v"(cb[ci][dq]) : "v"(cp + dq * 8));
        }
      }
      asm volatile("s_waitcnt vmcnt(0)" ::: "memory");
      __builtin_amdgcn_sched_barrier(0);   // rule #18: pin VALU uses after the wait

      const float inv = 1.0f / (float)(nc + 1);
      #pragma unroll
      for (int dq = 0; dq < 4; ++dq) {
        const float4 f0 = pre[2 * dq];
        const float4 f1 = pre[2 * dq + 1];
        float sm[8] = {f0.x, f0.y, f0.z, f0.w, f1.x, f1.y, f1.z, f1.w};
        float mn[8];
        #pragma unroll
        for (int qq = 0; qq < 8; ++qq) mn[qq] = sm[qq];
        #pragma unroll
        for (int ci = 0; ci < 4; ++ci) {
          if (ci < nc) {
            const v8s cv = __builtin_bit_cast(v8s, cb[ci][dq]);
            #pragma unroll
            for (int qq = 0; qq < 8; ++qq) {
              const float v = bf2f(cv[qq]);
              sm[qq] += v; mn[qq] = fminf(mn[qq], v);
            }
          }
        }
        v8s om, on;
        #pragma unroll
        for (int qq = 0; qq < 8; ++qq) { om[qq] = f2bf(sm[qq] * inv); on[qq] = f2bf(mn[qq]); }
        const int ch = (d0 + dq * 8) >> 3;
        *(v8s*)&Xs[(bl << 9) + ((ch ^ swb) << 3)]        = om;  // c_mean: k in [0,256)
        *(v8s*)&Xs[(bl << 9) + (((ch + 32) ^ swb) << 3)] = on;  // c_min:  k in [256,512)
      }
    }
    __syncthreads();   // Xs ready

    // ---- GEMM: [16 x K] @ Wt^T -> [16 x 256]; 2 waves x 128 cols each ----
    v4f acc[8];
    #pragma unroll
    for (int nt = 0; nt < 8; ++nt) acc[nt] = v4f{0.f, 0.f, 0.f, 0.f};

    const short* __restrict__ Wp = W + (size_t)(wave * 128 + ln15) * K + quad * 8;
    const int nkc = K >> 5;
    v8s bcur[8];
    #pragma unroll
    for (int nt = 0; nt < 8; ++nt) bcur[nt] = *(const v8s*)(Wp + (size_t)nt * 16 * K);
    for (int kc = 0; kc < nkc; ++kc) {
      const int kn = (kc + 1 < nkc) ? kc + 1 : kc;   // last iter: harmless re-load
      v8s bnxt[8];
      #pragma unroll
      for (int nt = 0; nt < 8; ++nt) bnxt[nt] = *(const v8s*)(Wp + (size_t)nt * 16 * K + kn * 32);
      const v8s af = *(const v8s*)&Xs[(ln15 << 9) + (((kc * 4 + quad) ^ rl3) << 3)];
      #pragma unroll
      for (int nt = 0; nt < 8; ++nt)
        acc[nt] = mfma16(af, bcur[nt], acc[nt]);
      #pragma unroll
      for (int nt = 0; nt < 8; ++nt) bcur[nt] = bnxt[nt];
    }

    // ---- epilogue: bias + sigmoid; state stored via sc0sc1 (coherent at IF) ----
    #pragma unroll
    for (int nt = 0; nt < 8; ++nt) {
      const int j = wave * 128 + nt * 16 + ln15;
      const float bs = leaf ? bia_in[nt] : bia_nn[nt];
      #pragma unroll
      for (int r = 0; r < 4; ++r) {
        const int bb = q * 16 + quad * 4 + r;
        const float v = sigmoidf(acc[nt][r] + bs);
        short* sp = state + ((size_t)node * BATCH + bb) * DIM + j;
        const int hv = (int)(unsigned short)f2bf(v);
        asm volatile("global_store_short %0, %1, off sc0 sc1" :: "v"(sp), "v"(hv));
        if (node == 0) out[bb * DIM + j] = v;
      }
    }

    asm volatile("s_waitcnt vmcnt(0)" ::: "memory");  // this thread's stores are at IF
    __syncthreads();                                  // => ALL threads' stores are at IF
    if (tid == 0)
      __hip_atomic_store(&done[item], 1,
                         __ATOMIC_RELAXED, __HIP_MEMORY_SCOPE_AGENT);
  }
}

extern "C" void kernel_launch(void* const* d_in, const int* in_sizes, int n_in,
                              void* d_out, int out_size, void* d_ws, size_t ws_size,
                              hipStream_t stream) {
  const int*   structure = (const int*)d_in[0];
  const float* features  = (const float*)d_in[1];
  const float* W_in      = (const float*)d_in[2];
  const float* b_in      = (const float*)d_in[3];
  const float* W_inner   = (const float*)d_in[4];
  const float* b_inner   = (const float*)d_in[5];
  float* out = (float*)d_out;

  char* ws = (char*)d_ws;
  short* state = (short*)ws;                                   // 2000*64*256*2 = 65,536,000 B
  size_t off = (size_t)NNODES * BATCH * DIM * 2;
  short* Wt_in = (short*)(ws + off);    off += 256 * 256 * 2;  // 131,072 B
  short* Wt_inner = (short*)(ws + off); off += 512 * 256 * 2;  // 262,144 B
  int* done = (int*)(ws + off);                                 // 4*2000*4 = 32,000 B

  prep_kernel<<<dim3(256), dim3(256), 0, stream>>>(W_in, W_inner, Wt_in, Wt_inner, done);

  // Cooperative capacity: never launch more blocks than are co-resident (R1 lesson).
  static int coop_grid = 0;
  if (coop_grid == 0) {
    int nb = 0;
    hipError_t err = hipOccupancyMaxActiveBlocksPerMultiprocessor(
        &nb, reinterpret_cast<const void*>(tree_kernel), BLOCK, 0);
    if (err != hipSuccess || nb < 1) nb = 1;
    long g = (long)nb * 256;
    if (g > MAXGRID) g = MAXGRID;
    coop_grid = (int)g;
  }

  void* args[9];
  args[0] = (void*)&structure;
  args[1] = (void*)&features;
  args[2] = (void*)&b_in;
  args[3] = (void*)&b_inner;
  args[4] = (void*)&Wt_in;
  args[5] = (void*)&Wt_inner;
  args[6] = (void*)&state;
  args[7] = (void*)&done;
  args[8] = (void*)&out;
  hipLaunchCooperativeKernel((void*)tree_kernel, dim3(coop_grid), dim3(BLOCK), args, 0, stream);
}

// Round 7
// 472.634 us; speedup vs baseline: 1.0453x; 1.0453x over previous
//
#include <hip/hip_runtime.h>

#define NNODES 2000
#define BATCH  64
#define DIM    256
#define BLOCK  128
#define MAXGRID 1024
#define TBLD   264   // transpose-buffer row stride in shorts (pad 256->264 spreads banks)

typedef __attribute__((ext_vector_type(8))) short  v8s;
typedef __attribute__((ext_vector_type(8))) __bf16 v8bf;
typedef __attribute__((ext_vector_type(4))) float  v4f;
typedef __attribute__((ext_vector_type(4))) int    v4i;

__device__ __forceinline__ short f2bf(float f) {
  unsigned u = __builtin_bit_cast(unsigned, f);
  u += 0x7FFFu + ((u >> 16) & 1u);            // RNE
  return (short)(u >> 16);
}
__device__ __forceinline__ float bf2f(short s) {
  unsigned u = ((unsigned)(unsigned short)s) << 16;
  return __builtin_bit_cast(float, u);
}
__device__ __forceinline__ v4f mfma16(v8s a, v8s b, v4f c) {
  return __builtin_amdgcn_mfma_f32_16x16x32_bf16(
      __builtin_bit_cast(v8bf, a), __builtin_bit_cast(v8bf, b), c, 0, 0, 0);
}
__device__ __forceinline__ float sigmoidf(float x) {
  return __builtin_amdgcn_rcpf(1.0f + __builtin_amdgcn_exp2f(-1.4426950408889634f * x));
}

// Prep: Wt_in[j][k] = bf16(W_in[k][j]) (256x256);
//       Wt_inner[j][k] = bf16(k<256 ? W_inner[k][j]+W_inner[k+256][j] : W_inner[k+256][j]) (256x512);
//       done[] = 0 (agent-scope so tree_kernel's relaxed loads see it).
__global__ void prep_kernel(const float* __restrict__ W_in, const float* __restrict__ W_inner,
                            short* __restrict__ Wt_in, short* __restrict__ Wt_inner,
                            int* __restrict__ done) {
  int idx = blockIdx.x * blockDim.x + threadIdx.x;
  int stride = gridDim.x * blockDim.x;
  for (int i = idx; i < 256 * 256; i += stride) {
    int j = i >> 8, k = i & 255;
    Wt_in[j * 256 + k] = f2bf(W_in[k * 256 + j]);
  }
  for (int i = idx; i < 256 * 512; i += stride) {
    int j = i >> 9, k = i & 511;
    float v = W_inner[(k + 256) * 256 + j];
    if (k < 256) v += W_inner[k * 256 + j];
    Wt_inner[j * 512 + k] = f2bf(v);
  }
  for (int i = idx; i < 4 * NNODES; i += stride)
    __hip_atomic_store(&done[i], 0, __ATOMIC_RELAXED, __HIP_MEMORY_SCOPE_AGENT);
}

// Dataflow tree evaluation, zero cache-flush fences (R4-verified sc0sc1/IF scheme).
// R4/R5/R6 measured per-item wall ~37us INDEPENDENT of item size (64/32/16 rows)
// and of concurrency -> the binding constraint is a shared invariant resource:
// Infinity-Fabric small-transaction throughput from the sc0sc1 traffic
// (4096 scattered 2B stores/item = partial-line RMWs; 1024 isolated 16B
// uncacheable child loads/item at 16B-per-64B-line utilization).
// R7: same dataflow, coalesced IF traffic:
//  - pooling remapped to (row = tid>>5, chunk = tid&31): each wave64 child-load
//    instruction reads 2 x 512B CONTIGUOUS rows (full-line IF utilization)
//  - epilogue routed through LDS transpose (reusing dead Xs): state stored as
//    4 x dwordx4/thread, 8KB contiguous per item, instead of 4096 2B scatters
// Item = 4*node + q; q covers batch rows [16q,16q+16) -- independent end-to-end
// chains. Deps have strictly larger item index; blocks walk descending strided by
// gridDim.x; all blocks co-resident (occupancy-derived cooperative grid).
__launch_bounds__(BLOCK, 2)
__global__ void tree_kernel(const int* __restrict__ structure, const float* __restrict__ features,
                            const float* __restrict__ b_in, const float* __restrict__ b_inner,
                            const short* __restrict__ Wt_in, const short* __restrict__ Wt_inner,
                            short* __restrict__ state, int* done, float* __restrict__ out) {
  // 16 batch rows x 512 k (bf16), XOR-swizzled chunks: phys chunk = (k>>3) ^ (row&7).
  // Reused after the GEMM as a [16][TBLD] transpose buffer (8448 shorts < 8192... fits: 16*264=4224 < 8192).
  __shared__ short Xs[16 * 512];   // 16 KiB

  const int tid  = threadIdx.x;
  const int wave = tid >> 6;       // 0..1
  const int lane = tid & 63;
  const int ln15 = lane & 15;
  const int quad = lane >> 4;
  const int rl3  = ln15 & 7;

  const int rowb = tid >> 5;       // 0..3: base row for pooling/stores (row = rowb + 4g)
  const int ch   = tid & 31;       // 0..31: 16B chunk within a 512B state row

  // j = wave*128 + nt*16 + ln15 is node-invariant: hoist bias loads
  float bia_in[8], bia_nn[8];
  #pragma unroll
  for (int nt = 0; nt < 8; ++nt) {
    const int j = wave * 128 + nt * 16 + ln15;
    bia_in[nt] = b_in[j];
    bia_nn[nt] = b_inner[j];
  }

  for (int item = 4 * NNODES - 1 - (int)blockIdx.x; item >= 0; item -= (int)gridDim.x) {
    const int node = item >> 2;
    const int q    = item & 3;
    const int s = structure[2 * node];
    const int e = structure[2 * node + 1];
    const bool leaf = (s < 0);
    const int nc = e - s;               // 1..4 when inner
    const int K = leaf ? 256 : 512;
    const short* __restrict__ W = leaf ? Wt_in : Wt_inner;

    // feature prefetch BEFORE the poll (plain cacheable loads; coalesced mapping)
    float4 pf[4][2];
    #pragma unroll
    for (int g = 0; g < 4; ++g) {
      const int b = q * 16 + rowb + 4 * g;
      const float* __restrict__ fp = features + ((size_t)b * NNODES + node) * DIM + ch * 8;
      pf[g][0] = ((const float4*)fp)[0];
      pf[g][1] = ((const float4*)fp)[1];
    }

    if (!leaf && wave == 0 && lane < nc) {
      // relaxed agent-scope poll (reads IF, no cache invalidation);
      // the nc flags share one 64B line -> one coalesced transaction per probe
      int g = 0;
      while (__hip_atomic_load(&done[4 * (s + lane) + q],
                               __ATOMIC_RELAXED, __HIP_MEMORY_SCOPE_AGENT) == 0 &&
             g < (1 << 22)) {
        __builtin_amdgcn_s_sleep(1); ++g;
      }
    }
    __syncthreads();   // children's quarter ready; also WAR on Xs from prior item

    // ---- build Xs (bf16): thread covers rows {rowb+4g}, 16B chunk ch ----
    if (leaf) {
      #pragma unroll
      for (int g = 0; g < 4; ++g) {
        const int row = rowb + 4 * g;
        const int sw  = row & 7;
        const float4 f0 = pf[g][0], f1 = pf[g][1];
        v8s o;
        o[0] = f2bf(f0.x); o[1] = f2bf(f0.y); o[2] = f2bf(f0.z); o[3] = f2bf(f0.w);
        o[4] = f2bf(f1.x); o[5] = f2bf(f1.y); o[6] = f2bf(f1.z); o[7] = f2bf(f1.w);
        *(v8s*)&Xs[(row << 9) + ((ch ^ sw) << 3)] = o;
      }
    } else {
      // child loads: sc0sc1 (bypass stale L1/L2, coherent at IF), COALESCED:
      // one instruction = 2 contiguous 512B rows across the wave. All issued,
      // then one waitcnt -- IF latency paid once.
      v4i cb[4][4];   // [ci][g]
      #pragma unroll
      for (int ci = 0; ci < 4; ++ci) {
        if (ci < nc) {   // block-uniform branch
          #pragma unroll
          for (int g = 0; g < 4; ++g) {
            const short* cp = state + ((size_t)(s + ci) * BATCH + q * 16 + rowb + 4 * g) * DIM + ch * 8;
            asm volatile("global_load_dwordx4 %0, %1, off sc0 sc1"
                         : "=v"(cb[ci][g]) : "v"(cp));
          }
        }
      }
      asm volatile("s_waitcnt vmcnt(0)" ::: "memory");
      __builtin_amdgcn_sched_barrier(0);   // rule #18: pin VALU uses after the wait

      const float inv = 1.0f / (float)(nc + 1);
      #pragma unroll
      for (int g = 0; g < 4; ++g) {
        const int row = rowb + 4 * g;
        const int sw  = row & 7;
        const float4 f0 = pf[g][0], f1 = pf[g][1];
        float sm[8] = {f0.x, f0.y, f0.z, f0.w, f1.x, f1.y, f1.z, f1.w};
        float mn[8];
        #pragma unroll
        for (int qq = 0; qq < 8; ++qq) mn[qq] = sm[qq];
        #pragma unroll
        for (int ci = 0; ci < 4; ++ci) {
          if (ci < nc) {
            const v8s cv = __builtin_bit_cast(v8s, cb[ci][g]);
            #pragma unroll
            for (int qq = 0; qq < 8; ++qq) {
              const float v = bf2f(cv[qq]);
              sm[qq] += v; mn[qq] = fminf(mn[qq], v);
            }
          }
        }
        v8s om, on;
        #pragma unroll
        for (int qq = 0; qq < 8; ++qq) { om[qq] = f2bf(sm[qq] * inv); on[qq] = f2bf(mn[qq]); }
        *(v8s*)&Xs[(row << 9) + ((ch ^ sw) << 3)]          = om;  // c_mean: k in [0,256)
        *(v8s*)&Xs[(row << 9) + (((ch + 32) ^ sw) << 3)]   = on;  // c_min:  k in [256,512)
      }
    }
    __syncthreads();   // Xs ready

    // ---- GEMM: [16 x K] @ Wt^T -> [16 x 256]; 2 waves x 128 cols each ----
    v4f acc[8];
    #pragma unroll
    for (int nt = 0; nt < 8; ++nt) acc[nt] = v4f{0.f, 0.f, 0.f, 0.f};

    const short* __restrict__ Wp = W + (size_t)(wave * 128 + ln15) * K + quad * 8;
    const int nkc = K >> 5;
    v8s bcur[8];
    #pragma unroll
    for (int nt = 0; nt < 8; ++nt) bcur[nt] = *(const v8s*)(Wp + (size_t)nt * 16 * K);
    for (int kc = 0; kc < nkc; ++kc) {
      const int kn = (kc + 1 < nkc) ? kc + 1 : kc;   // last iter: harmless re-load
      v8s bnxt[8];
      #pragma unroll
      for (int nt = 0; nt < 8; ++nt) bnxt[nt] = *(const v8s*)(Wp + (size_t)nt * 16 * K + kn * 32);
      const v8s af = *(const v8s*)&Xs[(ln15 << 9) + (((kc * 4 + quad) ^ rl3) << 3)];
      #pragma unroll
      for (int nt = 0; nt < 8; ++nt)
        acc[nt] = mfma16(af, bcur[nt], acc[nt]);
      #pragma unroll
      for (int nt = 0; nt < 8; ++nt) bcur[nt] = bnxt[nt];
    }
    __syncthreads();   // WAR: all Xs reads done before transpose-buffer overwrite

    // ---- epilogue: bias + sigmoid -> LDS transpose tile [16][TBLD] ----
    #pragma unroll
    for (int nt = 0; nt < 8; ++nt) {
      const int j = wave * 128 + nt * 16 + ln15;
      const float bs = leaf ? bia_in[nt] : bia_nn[nt];
      #pragma unroll
      for (int r = 0; r < 4; ++r) {
        const int bb = quad * 4 + r;           // 0..15 (row within quarter)
        const float v = sigmoidf(acc[nt][r] + bs);
        Xs[bb * TBLD + j] = f2bf(v);
        if (node == 0) out[(q * 16 + bb) * DIM + j] = v;   // exact fp32, node-0 only
      }
    }
    __syncthreads();   // transpose tile ready

    // ---- coalesced state store: 4 x dwordx4 sc0sc1 per thread (8KB contiguous) ----
    #pragma unroll
    for (int g = 0; g < 4; ++g) {
      const int row = rowb + 4 * g;
      const v4i val = *(const v4i*)&Xs[row * TBLD + ch * 8];
      short* sp = state + ((size_t)node * BATCH + q * 16 + row) * DIM + ch * 8;
      asm volatile("global_store_dwordx4 %0, %1, off sc0 sc1" :: "v"(sp), "v"(val));
    }

    asm volatile("s_waitcnt vmcnt(0)" ::: "memory");  // this thread's stores are at IF
    __syncthreads();                                  // => ALL threads' stores are at IF
    if (tid == 0)
      __hip_atomic_store(&done[item], 1,
                         __ATOMIC_RELAXED, __HIP_MEMORY_SCOPE_AGENT);
  }
}

extern "C" void kernel_launch(void* const* d_in, const int* in_sizes, int n_in,
                              void* d_out, int out_size, void* d_ws, size_t ws_size,
                              hipStream_t stream) {
  const int*   structure = (const int*)d_in[0];
  const float* features  = (const float*)d_in[1];
  const float* W_in      = (const float*)d_in[2];
  const float* b_in      = (const float*)d_in[3];
  const float* W_inner   = (const float*)d_in[4];
  const float* b_inner   = (const float*)d_in[5];
  float* out = (float*)d_out;

  char* ws = (char*)d_ws;
  short* state = (short*)ws;                                   // 2000*64*256*2 = 65,536,000 B
  size_t off = (size_t)NNODES * BATCH * DIM * 2;
  short* Wt_in = (short*)(ws + off);    off += 256 * 256 * 2;  // 131,072 B
  short* Wt_inner = (short*)(ws + off); off += 512 * 256 * 2;  // 262,144 B
  int* done = (int*)(ws + off);                                 // 4*2000*4 = 32,000 B

  prep_kernel<<<dim3(256), dim3(256), 0, stream>>>(W_in, W_inner, Wt_in, Wt_inner, done);

  // Cooperative capacity: never launch more blocks than are co-resident (R1 lesson).
  static int coop_grid = 0;
  if (coop_grid == 0) {
    int nb = 0;
    hipError_t err = hipOccupancyMaxActiveBlocksPerMultiprocessor(
        &nb, reinterpret_cast<const void*>(tree_kernel), BLOCK, 0);
    if (err != hipSuccess || nb < 1) nb = 1;
    long g = (long)nb * 256;
    if (g > MAXGRID) g = MAXGRID;
    coop_grid = (int)g;
  }

  void* args[9];
  args[0] = (void*)&structure;
  args[1] = (void*)&features;
  args[2] = (void*)&b_in;
  args[3] = (void*)&b_inner;
  args[4] = (void*)&Wt_in;
  args[5] = (void*)&Wt_inner;
  args[6] = (void*)&state;
  args[7] = (void*)&done;
  args[8] = (void*)&out;
  hipLaunchCooperativeKernel((void*)tree_kernel, dim3(coop_grid), dim3(BLOCK), args, 0, stream);
}